// Round 8
// baseline (32.166 us; speedup 1.0000x reference)
//
#include <hip/hip_runtime.h>

// T_lv2: out[0..4718591]        = fold(gather(unfold(ref_lv2,3,1,1)))/9  [4,128,96,96]
// T_lv1: out[4718592..9437183]  = fold(gather(unfold(ref_lv1,6,2,2)))/9  [4,64,192,192]
//
// R7: 2-position-per-iteration gather pipeline: 18 ds_read_b64 in flight
// before accumulation, tap-table prefetched 2 positions deep and issued
// BEFORE the stage loop. bf16 8B cells (4 values), 73.75KB LDS, 512 blocks
// x 512 thr (2 blocks/CU, lv1+lv2 pairing per CU via bid<256 split).

typedef float f2 __attribute__((ext_vector_type(2)));
typedef float f4 __attribute__((ext_vector_type(4)));

#define NINE_INV (1.0f / 9.0f)
#define ZCELL 9216u

__device__ __forceinline__ unsigned rne_bf16(float f) {
    unsigned u = __builtin_bit_cast(unsigned, f);
    return (u + 0x7fffu + ((u >> 16) & 1u)) >> 16;
}
__device__ __forceinline__ unsigned pack_bf2(float a, float b) {
    return rne_bf16(a) | (rne_bf16(b) << 16);
}
__device__ __forceinline__ f2 up2(unsigned w) {
    f2 r;
    r.x = __builtin_bit_cast(float, w << 16);
    r.y = __builtin_bit_cast(float, w & 0xffff0000u);
    return r;
}
template <typename T> __device__ __forceinline__ T ntload(const T* p) {
    return __builtin_nontemporal_load(p);
}
template <typename T> __device__ __forceinline__ void ntstore(T* p, T v) {
    __builtin_nontemporal_store(v, p);
}

__global__ __launch_bounds__(256) void table_kernel(
    const int* __restrict__ idx, uint4* __restrict__ tabA,
    unsigned short* __restrict__ tabB)
{
    int g = blockIdx.x * 256 + threadIdx.x;       // 0..36863
    int b = g / 9216;
    int u = g - b * 9216;
    const int* idxb = idx + b * 9216;
    int r = u / 96, t = u - 96 * r;
    unsigned e[9];
#pragma unroll
    for (int i = 0; i < 3; ++i) {
        int oy = r - 1 + i;
        bool oyv = (unsigned)oy < 96u;
#pragma unroll
        for (int j = 0; j < 3; ++j) {
            int ox = t - 1 + j;
            bool pv = oyv & ((unsigned)ox < 96u);
            int jv = idxb[pv ? oy * 96 + ox : 0];
            int jy = jv / 96, jx = jv - 96 * jy;
            int ysh = jy + 1 - i, xsh = jx + 1 - j;
            bool sv = pv & ((unsigned)ysh < 96u) & ((unsigned)xsh < 96u);
            e[i * 3 + j] = sv ? (unsigned)(ysh * 96 + xsh) : ZCELL;
        }
    }
    uint4 w;
    w.x = e[0] | (e[1] << 16);
    w.y = e[2] | (e[3] << 16);
    w.z = e[4] | (e[5] << 16);
    w.w = e[6] | (e[7] << 16);
    tabA[g] = w;
    tabB[g] = (unsigned short)e[8];
}

__device__ __forceinline__ void make_cells(const int* idxb, int u,
                                           uint4& A, unsigned& B)
{
    int r = u / 96, t = u - 96 * r;
    unsigned e[9];
#pragma unroll
    for (int i = 0; i < 3; ++i) {
        int oy = r - 1 + i;
        bool oyv = (unsigned)oy < 96u;
#pragma unroll
        for (int j = 0; j < 3; ++j) {
            int ox = t - 1 + j;
            bool pv = oyv & ((unsigned)ox < 96u);
            int jv = idxb[pv ? oy * 96 + ox : 0];
            int jy = jv / 96, jx = jv - 96 * jy;
            int ysh = jy + 1 - i, xsh = jx + 1 - j;
            bool sv = pv & ((unsigned)ysh < 96u) & ((unsigned)xsh < 96u);
            e[i * 3 + j] = sv ? (unsigned)(ysh * 96 + xsh) : ZCELL;
        }
    }
    A.x = e[0] | (e[1] << 16); A.y = e[2] | (e[3] << 16);
    A.z = e[4] | (e[5] << 16); A.w = e[6] | (e[7] << 16);
    B = e[8];
}

__device__ __forceinline__ void issue9(const unsigned* s2, uint4 cA, unsigned cB,
                                       uint2* d)
{
    d[0] = *(const uint2*)((const char*)s2 + ((cA.x & 0xffffu) << 3));
    d[1] = *(const uint2*)((const char*)s2 + ((cA.x >> 16) << 3));
    d[2] = *(const uint2*)((const char*)s2 + ((cA.y & 0xffffu) << 3));
    d[3] = *(const uint2*)((const char*)s2 + ((cA.y >> 16) << 3));
    d[4] = *(const uint2*)((const char*)s2 + ((cA.z & 0xffffu) << 3));
    d[5] = *(const uint2*)((const char*)s2 + ((cA.z >> 16) << 3));
    d[6] = *(const uint2*)((const char*)s2 + ((cA.w & 0xffffu) << 3));
    d[7] = *(const uint2*)((const char*)s2 + ((cA.w >> 16) << 3));
    d[8] = *(const uint2*)((const char*)s2 + ((unsigned)cB << 3));
}
__device__ __forceinline__ void accum9(const uint2* d, f2& a0, f2& a1)
{
#pragma unroll
    for (int p = 0; p < 9; ++p) {
        a0 += up2(d[p].x);
        a1 += up2(d[p].y);
    }
}

template <bool TAB>
__global__ __launch_bounds__(512, 4) void transfer_kernel(
    const int* __restrict__ idx,
    const float* __restrict__ ref1,
    const float* __restrict__ ref2,
    const uint4* __restrict__ tabA,
    const unsigned short* __restrict__ tabB,
    float* __restrict__ out)
{
    __shared__ __align__(16) unsigned s2[18436];
    const int tid = threadIdx.x;
    const int bid = blockIdx.x;
    const int b = bid & 3;

    if (tid < 4) s2[18432 + tid] = 0;

    const uint4* tA = tabA + b * 9216;
    const unsigned short* tB = tabB + b * 9216;
    const int* idxb = idx + b * 9216;
    const f2 nv = {NINE_INV, NINE_INV};

    if (bid < 256) {
        // ---------------- lv1 ----------------
        const int q = (bid >> 2) & 1, c0 = (bid >> 3) * 2;
        const float* g0 = ref1 + (size_t)(b * 64 + c0) * 36864;

        uint4 A0, A1; unsigned B0, B1;
        if (TAB) { A0 = tA[tid]; B0 = tB[tid]; A1 = tA[tid + 512]; B1 = tB[tid + 512]; }

#pragma unroll 3
        for (int u2 = tid; u2 < 4608; u2 += 512) {
            int ysh = u2 / 48, xsh0 = 2 * (u2 - 48 * ysh);
            const float* gp = g0 + (size_t)(2 * ysh + q) * 192 + 2 * xsh0;
            f4 va = ntload((const f4*)gp);
            f4 vb = ntload((const f4*)(gp + 36864));
            uint4 w;
            w.x = pack_bf2(va.x, va.y); w.y = pack_bf2(vb.x, vb.y);
            w.z = pack_bf2(va.z, va.w); w.w = pack_bf2(vb.z, vb.w);
            *(uint4*)(s2 + 4 * u2) = w;
        }
        __syncthreads();

        float* ob = out + 4718592 + (size_t)(b * 64 + c0) * 36864;

        int u = tid;
#pragma unroll
        for (int k = 0; k < 9; ++k) {
            if (!TAB) { make_cells(idxb, u, A0, B0); make_cells(idxb, u + 512, A1, B1); }
            uint2 d0[9], d1[9];
            issue9(s2, A0, B0, d0);
            issue9(s2, A1, B1, d1);
            uint4 P0 = A0, P1 = A1; unsigned Q0 = B0, Q1 = B1;
            if (TAB && k < 8) {
                P0 = tA[u + 1024]; Q0 = tB[u + 1024];
                P1 = tA[u + 1536]; Q1 = tB[u + 1536];
            }
            f2 a00 = {0.f, 0.f}, a01 = {0.f, 0.f};
            f2 a10 = {0.f, 0.f}, a11 = {0.f, 0.f};
            accum9(d0, a00, a01);
            accum9(d1, a10, a11);
            a00 *= nv; a01 *= nv; a10 *= nv; a11 *= nv;
            {
                int r = u / 96, t = u - 96 * r;
                float* op = ob + (size_t)(2 * r + q) * 192 + 2 * t;
                ntstore((f2*)op, a00);
                ntstore((f2*)(op + 36864), a01);
            }
            {
                int us = u + 512;
                int r = us / 96, t = us - 96 * r;
                float* op = ob + (size_t)(2 * r + q) * 192 + 2 * t;
                ntstore((f2*)op, a10);
                ntstore((f2*)(op + 36864), a11);
            }
            u += 1024;
            A0 = P0; B0 = Q0; A1 = P1; B1 = Q1;
        }
    } else {
        // ---------------- lv2 ----------------
        const int r2 = bid - 256;
        const int grp = (r2 >> 2) & 31, h = (r2 >> 7) & 1;
        const int c0 = grp * 4;
        const float* g0 = ref2 + (size_t)(b * 128 + c0) * 9216;
        const int u0 = h * 4608;

        uint4 A0, A1; unsigned B0, B1;
        if (TAB) {
            A0 = tA[u0 + tid]; B0 = tB[u0 + tid];
            A1 = tA[u0 + tid + 512]; B1 = tB[u0 + tid + 512];
        }

#pragma unroll 3
        for (int u2 = tid; u2 < 4608; u2 += 512) {
            f2 p0 = ntload((const f2*)(g0 + 2 * u2));
            f2 p1 = ntload((const f2*)(g0 + 9216 + 2 * u2));
            f2 p2 = ntload((const f2*)(g0 + 2 * 9216 + 2 * u2));
            f2 p3 = ntload((const f2*)(g0 + 3 * 9216 + 2 * u2));
            uint4 w;
            w.x = pack_bf2(p0.x, p1.x); w.y = pack_bf2(p2.x, p3.x);
            w.z = pack_bf2(p0.y, p1.y); w.w = pack_bf2(p2.y, p3.y);
            *(uint4*)(s2 + 4 * u2) = w;
        }
        __syncthreads();

        float* ob = out + (size_t)(b * 128 + c0) * 9216;

        int u = u0 + tid;
#pragma unroll
        for (int k = 0; k < 4; ++k) {
            if (!TAB) { make_cells(idxb, u, A0, B0); make_cells(idxb, u + 512, A1, B1); }
            uint2 d0[9], d1[9];
            issue9(s2, A0, B0, d0);
            issue9(s2, A1, B1, d1);
            uint4 P0 = A0, P1 = A1; unsigned Q0 = B0, Q1 = B1;
            if (TAB) {
                P0 = tA[u + 1024]; Q0 = tB[u + 1024];
                if (k < 3) { P1 = tA[u + 1536]; Q1 = tB[u + 1536]; }
            }
            f2 a00 = {0.f, 0.f}, a01 = {0.f, 0.f};
            f2 a10 = {0.f, 0.f}, a11 = {0.f, 0.f};
            accum9(d0, a00, a01);
            accum9(d1, a10, a11);
            a00 *= nv; a01 *= nv; a10 *= nv; a11 *= nv;
            {
                float* op = ob + u;
                ntstore(op, a00.x);             ntstore(op + 9216, a00.y);
                ntstore(op + 2 * 9216, a01.x);  ntstore(op + 3 * 9216, a01.y);
                float* op2 = ob + u + 512;
                ntstore(op2, a10.x);            ntstore(op2 + 9216, a10.y);
                ntstore(op2 + 2 * 9216, a11.x); ntstore(op2 + 3 * 9216, a11.y);
            }
            u += 1024;
            A0 = P0; B0 = Q0; A1 = P1; B1 = Q1;
        }
        {   // singleton: u = u0 + tid + 4096
            if (!TAB) make_cells(idxb, u, A0, B0);
            uint2 d0[9];
            issue9(s2, A0, B0, d0);
            f2 a00 = {0.f, 0.f}, a01 = {0.f, 0.f};
            accum9(d0, a00, a01);
            a00 *= nv; a01 *= nv;
            float* op = ob + u;
            ntstore(op, a00.x);            ntstore(op + 9216, a00.y);
            ntstore(op + 2 * 9216, a01.x); ntstore(op + 3 * 9216, a01.y);
        }
    }
}

extern "C" void kernel_launch(void* const* d_in, const int* in_sizes, int n_in,
                              void* d_out, int out_size, void* d_ws, size_t ws_size,
                              hipStream_t stream) {
    const int*   idx  = (const int*)d_in[0];
    const float* ref1 = (const float*)d_in[2];
    const float* ref2 = (const float*)d_in[3];
    float* outp = (float*)d_out;

    uint4* tabA = (uint4*)d_ws;
    unsigned short* tabB = (unsigned short*)((char*)d_ws + (size_t)4 * 9216 * 16);

    const size_t need = (size_t)4 * 9216 * 16 + (size_t)4 * 9216 * 2;  // 664 KB
    if (ws_size >= need) {
        hipLaunchKernelGGL(table_kernel, dim3(144), dim3(256), 0, stream,
                           idx, tabA, tabB);
        hipLaunchKernelGGL(transfer_kernel<true>, dim3(512), dim3(512), 0, stream,
                           idx, ref1, ref2, tabA, tabB, outp);
    } else {
        hipLaunchKernelGGL(transfer_kernel<false>, dim3(512), dim3(512), 0, stream,
                           idx, ref1, ref2, tabA, tabB, outp);
    }
}